// Round 11
// baseline (124.756 us; speedup 1.0000x reference)
//
#include <hip/hip_runtime.h>
#include <hip/hip_bf16.h>
#include <cstdint>
#include <cstddef>

#define NROWS 8192
#define KDIM  2048
#define ODIM  1000
#define NSUB  8
#define OPAD  1024   // padded output dim for Wt

#define BM 128
#define BN 128
#define BK 64
#define MT_MAX 10    // covers multinomial counts (<=1280 rows/subject)

typedef __attribute__((ext_vector_type(4))) float f32x4;
typedef __attribute__((ext_vector_type(8))) short short8v;
typedef __attribute__((ext_vector_type(4))) unsigned short u16x4;
typedef __attribute__((ext_vector_type(4))) int int4v;

__device__ __forceinline__ unsigned short f2bf(float f){
  unsigned u = __builtin_bit_cast(unsigned, f);
  unsigned r = (u + 0x7FFFu + ((u >> 16) & 1u)) >> 16;  // RNE
  return (unsigned short)r;
}

__device__ __forceinline__ void gload16(const void* g, void* l){
  __builtin_amdgcn_global_load_lds(
      (const __attribute__((address_space(1))) void*)g,
      (__attribute__((address_space(3))) void*)l, 16, 0, 0);
}

// ---------------- K1: build perm/counts/offsets in ONE kernel ----------------
__global__ __launch_bounds__(256) void build_perm(const int* __restrict__ sid,
                                                  int* __restrict__ counts,
                                                  int* __restrict__ offsets,
                                                  int* __restrict__ perm){
  int s = blockIdx.x;
  __shared__ int shs[NROWS];          // 32KB cached sid
  __shared__ int red_lt[4], red_eq[4], wsum[4];
  __shared__ int sh_base;

  int t = threadIdx.x, lane = t & 63, wv = t >> 6;

  int c_lt = 0, c_eq = 0;
  const int4v* sv = (const int4v*)sid;
  #pragma unroll
  for (int i = 0; i < NROWS / 4 / 256; i++){
    int idx = i * 256 + t;
    int4v v = sv[idx];
    *(int4v*)&shs[idx * 4] = v;
    #pragma unroll
    for (int e = 0; e < 4; e++){ c_lt += (v[e] < s); c_eq += (v[e] == s); }
  }
  #pragma unroll
  for (int d = 32; d >= 1; d >>= 1){
    c_lt += __shfl_xor(c_lt, d);
    c_eq += __shfl_xor(c_eq, d);
  }
  if (lane == 0){ red_lt[wv] = c_lt; red_eq[wv] = c_eq; }
  __syncthreads();
  if (t == 0){
    int lt = red_lt[0] + red_lt[1] + red_lt[2] + red_lt[3];
    int eq = red_eq[0] + red_eq[1] + red_eq[2] + red_eq[3];
    offsets[s] = lt;
    counts[s]  = eq;
    sh_base = lt;
  }
  __syncthreads();
  int base = sh_base;

  for (int c0 = 0; c0 < NROWS; c0 += 256){
    int v = shs[c0 + t];
    bool eq = (v == s);
    unsigned long long m = __ballot(eq);
    int rk = __popcll(m & ((1ull << lane) - 1ull));
    int wc = __popcll(m);
    if (lane == 0) wsum[wv] = wc;
    __syncthreads();
    int woff = 0;
    #pragma unroll
    for (int w = 0; w < 4; w++) if (w < wv) woff += wsum[w];
    int tot = wsum[0] + wsum[1] + wsum[2] + wsum[3];
    if (eq) perm[base + woff + rk] = c0 + t;
    base += tot;
    __syncthreads();
  }
}

// ---------------- K2: fused gather(x->xs bf16 sorted) + transpose(W->Wt bf16) ----------------
__global__ __launch_bounds__(256) void prep_fused(const float* __restrict__ x,
                                                  const int* __restrict__ perm,
                                                  unsigned short* __restrict__ xs,
                                                  const float* __restrict__ W,
                                                  unsigned short* __restrict__ Wt){
  __shared__ float tile[64][65];
  int b = blockIdx.x;
  int t = threadIdx.x;
  if (b < NROWS){
    int orow = perm[b];
    const f32x4* src = (const f32x4*)(x + (size_t)orow * KDIM);
    u16x4* dst = (u16x4*)(xs + (size_t)b * KDIM);
    #pragma unroll
    for (int c = 0; c < 2; c++){
      f32x4 v = src[c * 256 + t];
      u16x4 o;
      o[0] = f2bf(v[0]); o[1] = f2bf(v[1]); o[2] = f2bf(v[2]); o[3] = f2bf(v[3]);
      dst[c * 256 + t] = o;
    }
    return;
  }
  int b2 = b - NROWS;
  int s  = b2 >> 9;
  int kt = (b2 >> 4) & 31;
  int ot = b2 & 15;
  int k0 = kt * 64, o0 = ot * 64;
  int ol = t & 63, kr = t >> 6;
  const float* src = W + ((size_t)s * KDIM + k0) * ODIM + o0;
  bool oval = (o0 + ol) < ODIM;
  #pragma unroll
  for (int it = 0; it < 16; it++){
    int k = kr * 16 + it;
    tile[k][ol] = oval ? src[(size_t)k * ODIM + ol] : 0.f;
  }
  __syncthreads();
  int kp = t & 31, orow = t >> 5;
  unsigned short* dst = Wt + ((size_t)(s * OPAD + o0)) * KDIM + k0;
  #pragma unroll
  for (int it = 0; it < 8; it++){
    int o = orow + it * 8;
    bool valid = (o0 + o) < ODIM;        // pad rows -> zeros
    unsigned lo = valid ? (unsigned)f2bf(tile[kp * 2][o])     : 0u;
    unsigned hi = valid ? (unsigned)f2bf(tile[kp * 2 + 1][o]) : 0u;
    *(unsigned*)(dst + (size_t)o * KDIM + kp * 2) = lo | (hi << 16);
  }
}

// ---------------- K3: grouped bf16 MFMA GEMM ----------------
// 128x128, BK=64, R4-verified conflict-free XOR swizzle, 2-slot LDS dbuf,
// 1-tile prefetch (A early / B late), ONE {vmcnt(0)+barrier} per K-tile.
// R11 change: tile body is PURE C++ (no manual lgkmcnt / sched_barrier /
// setprio) so the compiler emits fine-grained counted lgkmcnt and
// interleaves ds_read returns with MFMA issue (kills the lgkm convoy).
__global__ __launch_bounds__(256, 2) void gemm_bf16(
    const unsigned short* __restrict__ xs,   // [8192][2048] bf16 (sorted)
    const unsigned short* __restrict__ Wt,   // [8][1024][2048] bf16
    const int* __restrict__ counts,
    const int* __restrict__ offsets,
    const int* __restrict__ perm,
    const float* __restrict__ bias,          // [8][1000]
    float* __restrict__ out)                 // [8192][1000]
{
  int b  = blockIdx.x;
  int s  = b & 7;                 // subject == XCD (hw round-robins bid%8)
  int r  = b >> 3;
  int nt = r & 7;                 // 0..7
  int mt = r >> 3;                // 0..9
  int cnt = counts[s];
  int loc0 = mt * BM;
  if (loc0 >= cnt) return;
  int row0 = offsets[s] + loc0;
  int cnt_loc = cnt - loc0;

  __shared__ unsigned short lA[2][BM * BK];  // 2 x 16KB
  __shared__ unsigned short lB[2][BN * BK];  // 2 x 16KB
  __shared__ int permL[BM];

  int t = threadIdx.x;
  int lane = t & 63;
  int wave = t >> 6;

  int wm = (wave >> 1) << 6;      // 2x2 waves, wave-tile 64x64
  int wn = (wave & 1) << 6;
  int frow = lane & 15, fk = lane >> 4;
  int axor = frow & 7;

  // staging geometry (R4-verified, 0 bank conflicts):
  // 1KB chunk cb = rows cb*8..cb*8+7 x 64k; phys 16B-slot (lane&7) holds
  // logical slot (lane&7)^(row&7); read back at phys (j ^ (row&7)).
  int srck = (((lane & 7) ^ ((lane >> 3) & 7)) << 3);
  size_t gA[4], gB[4];
  unsigned lo[4];
  #pragma unroll
  for (int it = 0; it < 4; it++){
    int cb  = it * 4 + wave;               // 0..15
    int row = (cb << 3) + (lane >> 3);     // 0..127
    int ra  = row0 + row; if (ra > NROWS - 1) ra = NROWS - 1;
    gA[it] = (size_t)ra * KDIM + srck;
    gB[it] = ((size_t)(s * OPAD + nt * BN + row)) * KDIM + srck;
    lo[it] = (unsigned)((cb << 9) + (lane << 3));
  }

  f32x4 acc[4][4];
  #pragma unroll
  for (int i = 0; i < 4; i++)
    #pragma unroll
    for (int j = 0; j < 4; j++)
      #pragma unroll
      for (int e = 0; e < 4; e++) acc[i][j][e] = 0.f;

#define STAGE_A(slot, koff) do { \
    gload16(xs + gA[0] + (koff), (void*)(&lA[slot][lo[0]])); \
    gload16(xs + gA[1] + (koff), (void*)(&lA[slot][lo[1]])); \
    gload16(xs + gA[2] + (koff), (void*)(&lA[slot][lo[2]])); \
    gload16(xs + gA[3] + (koff), (void*)(&lA[slot][lo[3]])); \
  } while (0)
#define STAGE_B(slot, koff) do { \
    gload16(Wt + gB[0] + (koff), (void*)(&lB[slot][lo[0]])); \
    gload16(Wt + gB[1] + (koff), (void*)(&lB[slot][lo[1]])); \
    gload16(Wt + gB[2] + (koff), (void*)(&lB[slot][lo[2]])); \
    gload16(Wt + gB[3] + (koff), (void*)(&lB[slot][lo[3]])); \
  } while (0)

// tile-start: this tile's staging landed (issued a full tile ago), all
// waves arrived. The only asm sync in the loop.
#define TS() do { \
    asm volatile("s_waitcnt vmcnt(0)" ::: "memory"); \
    __builtin_amdgcn_s_barrier(); \
  } while (0)

#define AOFF(mi, ks) (((wm + ((mi) << 4) + frow) << 6) + ((((ks) * 4 + fk) ^ axor) << 3))
#define BOFF(ni, ks) (((wn + ((ni) << 4) + frow) << 6) + ((((ks) * 4 + fk) ^ axor) << 3))
#define MF(mi, ni, av, bv) acc[mi][ni] = __builtin_amdgcn_mfma_f32_16x16x32_bf16(av, bv, acc[mi][ni], 0, 0, 0)

// one K-tile: 16 ds_read_b128 + 32 MFMA, COMPILER-scheduled (fine lgkmcnt).
// staging for the next tile interleaved: A after ks0 reads, B after ks1.
#define TILE(sl, STG_A, STG_B) do { \
    short8v a00 = *(const short8v*)&lA[sl][AOFF(0, 0)]; \
    short8v a10 = *(const short8v*)&lA[sl][AOFF(1, 0)]; \
    short8v a20 = *(const short8v*)&lA[sl][AOFF(2, 0)]; \
    short8v a30 = *(const short8v*)&lA[sl][AOFF(3, 0)]; \
    short8v b00 = *(const short8v*)&lB[sl][BOFF(0, 0)]; \
    short8v b10 = *(const short8v*)&lB[sl][BOFF(1, 0)]; \
    short8v b20 = *(const short8v*)&lB[sl][BOFF(2, 0)]; \
    short8v b30 = *(const short8v*)&lB[sl][BOFF(3, 0)]; \
    STG_A; \
    short8v a01 = *(const short8v*)&lA[sl][AOFF(0, 1)]; \
    short8v a11 = *(const short8v*)&lA[sl][AOFF(1, 1)]; \
    short8v a21 = *(const short8v*)&lA[sl][AOFF(2, 1)]; \
    short8v a31 = *(const short8v*)&lA[sl][AOFF(3, 1)]; \
    short8v b01 = *(const short8v*)&lB[sl][BOFF(0, 1)]; \
    short8v b11 = *(const short8v*)&lB[sl][BOFF(1, 1)]; \
    short8v b21 = *(const short8v*)&lB[sl][BOFF(2, 1)]; \
    short8v b31 = *(const short8v*)&lB[sl][BOFF(3, 1)]; \
    STG_B; \
    MF(0, 0, a00, b00); MF(1, 0, a10, b00); MF(2, 0, a20, b00); MF(3, 0, a30, b00); \
    MF(0, 1, a00, b10); MF(1, 1, a10, b10); MF(2, 1, a20, b10); MF(3, 1, a30, b10); \
    MF(0, 2, a00, b20); MF(1, 2, a10, b20); MF(2, 2, a20, b20); MF(3, 2, a30, b20); \
    MF(0, 3, a00, b30); MF(1, 3, a10, b30); MF(2, 3, a20, b30); MF(3, 3, a30, b30); \
    MF(0, 0, a01, b01); MF(1, 0, a11, b01); MF(2, 0, a21, b01); MF(3, 0, a31, b01); \
    MF(0, 1, a01, b11); MF(1, 1, a11, b11); MF(2, 1, a21, b11); MF(3, 1, a31, b11); \
    MF(0, 2, a01, b21); MF(1, 2, a11, b21); MF(2, 2, a21, b21); MF(3, 2, a31, b21); \
    MF(0, 3, a01, b31); MF(1, 3, a11, b31); MF(2, 3, a21, b31); MF(3, 3, a31, b31); \
  } while (0)

  // prologue: permL + tile 0 staged into slot 0
  {
    int pr = t & 127;
    int pidx = row0 + pr; if (pidx > NROWS - 1) pidx = NROWS - 1;
    permL[pr] = perm[pidx];
  }
  STAGE_A(0, 0);
  STAGE_B(0, 0);

  // main loop: iteration i = tiles 2i (slot0) and 2i+1 (slot1); branch-free
  for (int i = 0; i < 15; ++i){
    int kb = i * 2 * BK;
    TS();
    TILE(0, STAGE_A(1, kb + BK),     STAGE_B(1, kb + BK));      // tile 2i
    TS();
    TILE(1, STAGE_A(0, kb + 2 * BK), STAGE_B(0, kb + 2 * BK));  // tile 2i+1
  }
  TS();
  TILE(0, STAGE_A(1, 31 * BK), STAGE_B(1, 31 * BK));            // tile 30
  TS();
  TILE(1, , );                                                  // tile 31

  // epilogue: C/D layout col=lane&15, row=(lane>>4)*4+reg
  float bvn[4]; int ocol[4];
  #pragma unroll
  for (int ni = 0; ni < 4; ni++){
    int o = (nt << 7) + wn + (ni << 4) + frow;
    ocol[ni] = o;
    bvn[ni] = (o < ODIM) ? bias[s * ODIM + o] : 0.f;
  }
  #pragma unroll
  for (int mi = 0; mi < 4; mi++){
    int rbase = wm + (mi << 4) + (fk << 2);
    #pragma unroll
    for (int jj = 0; jj < 4; jj++){
      int rr = rbase + jj;
      if (rr < cnt_loc){
        int orow = permL[rr];
        #pragma unroll
        for (int ni = 0; ni < 4; ni++){
          if (ocol[ni] < ODIM)
            out[(size_t)orow * ODIM + ocol[ni]] = acc[mi][ni][jj] + bvn[ni];
        }
      }
    }
  }
#undef STAGE_A
#undef STAGE_B
#undef TS
#undef AOFF
#undef BOFF
#undef MF
#undef TILE
}

// ---------------- fallback: naive fp32 (only if ws too small) ----------------
__global__ __launch_bounds__(256) void naive_kernel(const float* __restrict__ x,
                                                    const int* __restrict__ sid,
                                                    const float* __restrict__ W,
                                                    const float* __restrict__ bias,
                                                    float* __restrict__ out){
  __shared__ float xr[KDIM];
  int row = blockIdx.x;
  int s = sid[row];
  for (int i = threadIdx.x; i < KDIM; i += 256) xr[i] = x[(size_t)row * KDIM + i];
  __syncthreads();
  int o = blockIdx.y * 256 + threadIdx.x;
  if (o >= ODIM) return;
  const float* w = W + (size_t)s * KDIM * ODIM + o;
  float acc = bias[s * ODIM + o];
  for (int k = 0; k < KDIM; k++) acc = fmaf(xr[k], w[(size_t)k * ODIM], acc);
  out[(size_t)row * ODIM + o] = acc;
}

extern "C" void kernel_launch(void* const* d_in, const int* in_sizes, int n_in,
                              void* d_out, int out_size, void* d_ws, size_t ws_size,
                              hipStream_t stream) {
  const float* x    = (const float*)d_in[0];
  const int*   sid  = (const int*)d_in[1];
  const float* W    = (const float*)d_in[2];
  const float* bias = (const float*)d_in[3];
  float* out = (float*)d_out;

  const size_t XS_BYTES = (size_t)NROWS * KDIM * 2;
  const size_t WT_BYTES = (size_t)NSUB * OPAD * KDIM * 2;
  const size_t need = 64 + (size_t)NROWS * 4 + XS_BYTES + WT_BYTES;

  if (ws_size < need){
    naive_kernel<<<dim3(NROWS, 4), 256, 0, stream>>>(x, sid, W, bias, out);
    return;
  }

  char* w = (char*)d_ws;
  int* counts  = (int*)w;                      // 8 ints
  int* offsets = counts + 8;                   // 8 ints
  int* perm    = (int*)(w + 64);               // 8192 ints
  unsigned short* xs = (unsigned short*)(w + 64 + (size_t)NROWS * 4);
  unsigned short* Wt = xs + (size_t)NROWS * KDIM;

  build_perm <<<NSUB, 256, 0, stream>>>(sid, counts, offsets, perm);
  prep_fused <<<NROWS + 4096, 256, 0, stream>>>(x, perm, xs, W, Wt);
  gemm_bf16  <<<NSUB * 8 * MT_MAX, 256, 0, stream>>>(xs, Wt, counts, offsets, perm, bias, out);
}

// Round 12
// 112.534 us; speedup vs baseline: 1.1086x; 1.1086x over previous
//
#include <hip/hip_runtime.h>
#include <hip/hip_bf16.h>
#include <cstdint>
#include <cstddef>

#define NROWS 8192
#define KDIM  2048
#define ODIM  1000
#define NSUB  8
#define OPAD  1024   // padded output dim for Wt

#define BM 160
#define BN 256
#define BK 64
#define MT_MAX 8                 // 8 x 160 = 1280 rows/subject covered
#define ASLOT (BM * BK)          // 10240 elems (20KB)
#define SLOT  ((BM + BN) * BK)   // 26624 elems (53248B)

typedef __attribute__((ext_vector_type(4))) float f32x4;
typedef __attribute__((ext_vector_type(8))) short short8v;
typedef __attribute__((ext_vector_type(4))) unsigned short u16x4;
typedef __attribute__((ext_vector_type(4))) int int4v;

__device__ __forceinline__ unsigned short f2bf(float f){
  unsigned u = __builtin_bit_cast(unsigned, f);
  unsigned r = (u + 0x7FFFu + ((u >> 16) & 1u)) >> 16;  // RNE
  return (unsigned short)r;
}

__device__ __forceinline__ void gload16(const void* g, void* l){
  __builtin_amdgcn_global_load_lds(
      (const __attribute__((address_space(1))) void*)g,
      (__attribute__((address_space(3))) void*)l, 16, 0, 0);
}

// ---------------- K1: build perm/counts/offsets in ONE kernel ----------------
__global__ __launch_bounds__(256) void build_perm(const int* __restrict__ sid,
                                                  int* __restrict__ counts,
                                                  int* __restrict__ offsets,
                                                  int* __restrict__ perm){
  int s = blockIdx.x;
  __shared__ int shs[NROWS];          // 32KB cached sid
  __shared__ int red_lt[4], red_eq[4], wsum[4];
  __shared__ int sh_base;

  int t = threadIdx.x, lane = t & 63, wv = t >> 6;

  int c_lt = 0, c_eq = 0;
  const int4v* sv = (const int4v*)sid;
  #pragma unroll
  for (int i = 0; i < NROWS / 4 / 256; i++){
    int idx = i * 256 + t;
    int4v v = sv[idx];
    *(int4v*)&shs[idx * 4] = v;
    #pragma unroll
    for (int e = 0; e < 4; e++){ c_lt += (v[e] < s); c_eq += (v[e] == s); }
  }
  #pragma unroll
  for (int d = 32; d >= 1; d >>= 1){
    c_lt += __shfl_xor(c_lt, d);
    c_eq += __shfl_xor(c_eq, d);
  }
  if (lane == 0){ red_lt[wv] = c_lt; red_eq[wv] = c_eq; }
  __syncthreads();
  if (t == 0){
    int lt = red_lt[0] + red_lt[1] + red_lt[2] + red_lt[3];
    int eq = red_eq[0] + red_eq[1] + red_eq[2] + red_eq[3];
    offsets[s] = lt;
    counts[s]  = eq;
    sh_base = lt;
  }
  __syncthreads();
  int base = sh_base;

  for (int c0 = 0; c0 < NROWS; c0 += 256){
    int v = shs[c0 + t];
    bool eq = (v == s);
    unsigned long long m = __ballot(eq);
    int rk = __popcll(m & ((1ull << lane) - 1ull));
    int wc = __popcll(m);
    if (lane == 0) wsum[wv] = wc;
    __syncthreads();
    int woff = 0;
    #pragma unroll
    for (int w = 0; w < 4; w++) if (w < wv) woff += wsum[w];
    int tot = wsum[0] + wsum[1] + wsum[2] + wsum[3];
    if (eq) perm[base + woff + rk] = c0 + t;
    base += tot;
    __syncthreads();
  }
}

// ---------------- K2: fused gather(x->xs bf16 sorted) + transpose(W->Wt bf16) ----------------
__global__ __launch_bounds__(256) void prep_fused(const float* __restrict__ x,
                                                  const int* __restrict__ perm,
                                                  unsigned short* __restrict__ xs,
                                                  const float* __restrict__ W,
                                                  unsigned short* __restrict__ Wt){
  __shared__ float tile[64][65];
  int b = blockIdx.x;
  int t = threadIdx.x;
  if (b < NROWS){
    int orow = perm[b];
    const f32x4* src = (const f32x4*)(x + (size_t)orow * KDIM);
    u16x4* dst = (u16x4*)(xs + (size_t)b * KDIM);
    #pragma unroll
    for (int c = 0; c < 2; c++){
      f32x4 v = src[c * 256 + t];
      u16x4 o;
      o[0] = f2bf(v[0]); o[1] = f2bf(v[1]); o[2] = f2bf(v[2]); o[3] = f2bf(v[3]);
      dst[c * 256 + t] = o;
    }
    return;
  }
  int b2 = b - NROWS;
  int s  = b2 >> 9;
  int kt = (b2 >> 4) & 31;
  int ot = b2 & 15;
  int k0 = kt * 64, o0 = ot * 64;
  int ol = t & 63, kr = t >> 6;
  const float* src = W + ((size_t)s * KDIM + k0) * ODIM + o0;
  bool oval = (o0 + ol) < ODIM;
  #pragma unroll
  for (int it = 0; it < 16; it++){
    int k = kr * 16 + it;
    tile[k][ol] = oval ? src[(size_t)k * ODIM + ol] : 0.f;
  }
  __syncthreads();
  int kp = t & 31, orow = t >> 5;
  unsigned short* dst = Wt + ((size_t)(s * OPAD + o0)) * KDIM + k0;
  #pragma unroll
  for (int it = 0; it < 8; it++){
    int o = orow + it * 8;
    bool valid = (o0 + o) < ODIM;        // pad rows -> zeros
    unsigned lo = valid ? (unsigned)f2bf(tile[kp * 2][o])     : 0u;
    unsigned hi = valid ? (unsigned)f2bf(tile[kp * 2 + 1][o]) : 0u;
    *(unsigned*)(dst + (size_t)o * KDIM + kp * 2) = lo | (hi << 16);
  }
}

// ---------------- K3: grouped bf16 MFMA GEMM, 160x256, 8 waves, 3-slot ring ----------------
// R9 schedule (measured ~40% per-CU efficiency) with BM=160 so every subject
// fits in <=8 m-tiles -> <=32 active blocks per 32-CU XCD -> ONE dispatch
// round (R9's only loss was 2-round quantization at BM=128).
// Staging: 52 x 1KB chunks/slot; waves 0-3 carry 7, waves 4-7 carry 6 ->
// per-wave-group counted vmcnt literals (7/6), never draining in the loop.
__global__ __launch_bounds__(512, 1) void gemm_bf16(
    const unsigned short* __restrict__ xs,   // [8192][2048] bf16 (sorted)
    const unsigned short* __restrict__ Wt,   // [8][1024][2048] bf16
    const int* __restrict__ counts,
    const int* __restrict__ offsets,
    const int* __restrict__ perm,
    const float* __restrict__ bias,          // [8][1000]
    float* __restrict__ out)                 // [8192][1000]
{
  int b  = blockIdx.x;
  int s  = b & 7;                 // subject == XCD (hw round-robins bid%8)
  int r  = b >> 3;
  int nt = r & 3;                 // 0..3 (256-col tiles over OPAD)
  int mt = r >> 2;                // 0..7
  int cnt = counts[s];
  int loc0 = mt * BM;
  if (loc0 >= cnt) return;
  int row0 = offsets[s] + loc0;
  int cnt_loc = cnt - loc0;

  __shared__ unsigned short L[3 * SLOT];     // 3 x 53248B ring (159744B)
  __shared__ int permL[BM];                  // +640B => 160384 <= 163840

  int t = threadIdx.x;
  int lane = t & 63;
  int wave = t >> 6;              // 0..7

  int wm = (wave >> 2) * 80;      // 2M x 4N waves; wave-tile 80x64
  int wn = (wave & 3) << 6;
  int frow = lane & 15, fk = lane >> 4;
  int axor = frow & 7;

  // staging geometry (R4-verified, 0 bank conflicts): 1KB chunk = 8 rows x
  // 128B; phys 16B-slot (lane&7) holds logical (lane&7)^(row&7).
  int srck = (((lane & 7) ^ ((lane >> 3) & 7)) << 3);
  size_t gA[5]; unsigned loA[5];
  size_t gB[6]; unsigned loB[6];
  if (wave < 4){
    #pragma unroll
    for (int i = 0; i < 5; i++){
      int ca  = wave * 5 + i;                // 0..19
      int row = (ca << 3) + (lane >> 3);     // 0..159
      int ra  = row0 + row; if (ra > NROWS - 1) ra = NROWS - 1;
      gA[i]  = (size_t)ra * KDIM + srck;
      loA[i] = (unsigned)((ca << 9) + (lane << 3));
    }
    #pragma unroll
    for (int j = 0; j < 2; j++){
      int cb  = wave * 2 + j;                // 0..7
      int row = (cb << 3) + (lane >> 3);     // 0..63
      gB[j]  = ((size_t)(s * OPAD + nt * BN + row)) * KDIM + srck;
      loB[j] = (unsigned)(ASLOT + (cb << 9) + (lane << 3));
    }
  } else {
    #pragma unroll
    for (int j = 0; j < 6; j++){
      int cb  = 8 + (wave - 4) * 6 + j;      // 8..31
      int row = (cb << 3) + (lane >> 3);     // 64..255
      gB[j]  = ((size_t)(s * OPAD + nt * BN + row)) * KDIM + srck;
      loB[j] = (unsigned)(ASLOT + (cb << 9) + (lane << 3));
    }
  }

  f32x4 acc[5][4];
  #pragma unroll
  for (int i = 0; i < 5; i++)
    #pragma unroll
    for (int j = 0; j < 4; j++)
      #pragma unroll
      for (int e = 0; e < 4; e++) acc[i][j][e] = 0.f;

#define STAGE(sl, koff) do { \
    unsigned short* Ls = &L[(sl) * SLOT]; \
    if (wave < 4){ \
      gload16(xs + gA[0] + (koff), (void*)(Ls + loA[0])); \
      gload16(xs + gA[1] + (koff), (void*)(Ls + loA[1])); \
      gload16(xs + gA[2] + (koff), (void*)(Ls + loA[2])); \
      gload16(xs + gA[3] + (koff), (void*)(Ls + loA[3])); \
      gload16(xs + gA[4] + (koff), (void*)(Ls + loA[4])); \
      gload16(Wt + gB[0] + (koff), (void*)(Ls + loB[0])); \
      gload16(Wt + gB[1] + (koff), (void*)(Ls + loB[1])); \
    } else { \
      gload16(Wt + gB[0] + (koff), (void*)(Ls + loB[0])); \
      gload16(Wt + gB[1] + (koff), (void*)(Ls + loB[1])); \
      gload16(Wt + gB[2] + (koff), (void*)(Ls + loB[2])); \
      gload16(Wt + gB[3] + (koff), (void*)(Ls + loB[3])); \
      gload16(Wt + gB[4] + (koff), (void*)(Ls + loB[4])); \
      gload16(Wt + gB[5] + (koff), (void*)(Ls + loB[5])); \
    } \
  } while (0)

// tile-start: wait own oldest stage (7 or 6 loads); next stage stays in flight
#define TS() do { \
    if (wave < 4) asm volatile("s_waitcnt vmcnt(7)" ::: "memory"); \
    else          asm volatile("s_waitcnt vmcnt(6)" ::: "memory"); \
    __builtin_amdgcn_sched_barrier(0); \
    __builtin_amdgcn_s_barrier(); \
    __builtin_amdgcn_sched_barrier(0); \
  } while (0)

#define TS0() do { \
    asm volatile("s_waitcnt vmcnt(0)" ::: "memory"); \
    __builtin_amdgcn_sched_barrier(0); \
    __builtin_amdgcn_s_barrier(); \
    __builtin_amdgcn_sched_barrier(0); \
  } while (0)

#define AOFF(mi, ks) (((wm + ((mi) << 4) + frow) << 6) + ((((ks) * 4 + fk) ^ axor) << 3))
#define BOFF(ni, ks) (ASLOT + ((wn + ((ni) << 4) + frow) << 6) + ((((ks) * 4 + fk) ^ axor) << 3))
#define MF(mi, ni, av, bv) acc[mi][ni] = __builtin_amdgcn_mfma_f32_16x16x32_bf16(av, bv, acc[mi][ni], 0, 0, 0)

// one ks-phase: 9 ds_read_b128 -> lgkm drain -> 20 MFMA (setprio'd)
#define PHASE(sl, ks) do { \
    const unsigned short* Lb = &L[(sl) * SLOT]; \
    short8v a0 = *(const short8v*)&Lb[AOFF(0, ks)]; \
    short8v a1 = *(const short8v*)&Lb[AOFF(1, ks)]; \
    short8v a2 = *(const short8v*)&Lb[AOFF(2, ks)]; \
    short8v a3 = *(const short8v*)&Lb[AOFF(3, ks)]; \
    short8v a4 = *(const short8v*)&Lb[AOFF(4, ks)]; \
    short8v b0 = *(const short8v*)&Lb[BOFF(0, ks)]; \
    short8v b1 = *(const short8v*)&Lb[BOFF(1, ks)]; \
    short8v b2 = *(const short8v*)&Lb[BOFF(2, ks)]; \
    short8v b3 = *(const short8v*)&Lb[BOFF(3, ks)]; \
    asm volatile("s_waitcnt lgkmcnt(0)" ::: "memory"); \
    __builtin_amdgcn_sched_barrier(0); \
    __builtin_amdgcn_s_setprio(1); \
    MF(0, 0, a0, b0); MF(1, 0, a1, b0); MF(2, 0, a2, b0); MF(3, 0, a3, b0); MF(4, 0, a4, b0); \
    MF(0, 1, a0, b1); MF(1, 1, a1, b1); MF(2, 1, a2, b1); MF(3, 1, a3, b1); MF(4, 1, a4, b1); \
    MF(0, 2, a0, b2); MF(1, 2, a1, b2); MF(2, 2, a2, b2); MF(3, 2, a3, b2); MF(4, 2, a4, b2); \
    MF(0, 3, a0, b3); MF(1, 3, a1, b3); MF(2, 3, a2, b3); MF(3, 3, a3, b3); MF(4, 3, a4, b3); \
    __builtin_amdgcn_s_setprio(0); \
  } while (0)

#define TILE(sl) do { PHASE(sl, 0); PHASE(sl, 1); } while (0)

  // prologue: perm -> permL (drained BEFORE staging so vmcnt counts stay exact)
  {
    int pr = t;
    if (pr >= 320) pr -= 320;
    if (pr >= 160) pr -= 160;               // pr in [0,160), duplicates benign
    int pidx = row0 + pr; if (pidx > NROWS - 1) pidx = NROWS - 1;
    int pl = perm[pidx];
    asm volatile("s_waitcnt vmcnt(0)" ::: "memory");
    __builtin_amdgcn_sched_barrier(0);
    permL[pr] = pl;
  }
  STAGE(0, 0);
  STAGE(1, BK);

  // main loop: tiles 0..29 (10 iters x 3, static slots); stage t+2 after TS
  for (int i = 0; i < 10; ++i){
    int kb = i * 3 * BK;
    TS(); STAGE(2, kb + 2 * BK); TILE(0);
    TS(); STAGE(0, kb + 3 * BK); TILE(1);
    TS(); STAGE(1, kb + 4 * BK); TILE(2);
  }
  // tail: tiles 30 (slot 0), 31 (slot 1)
  TS();  TILE(0);
  TS0(); TILE(1);

  // epilogue: C/D layout col=lane&15, row=(lane>>4)*4+reg
  float bvn[4]; int ocol[4];
  #pragma unroll
  for (int ni = 0; ni < 4; ni++){
    int o = nt * BN + wn + (ni << 4) + frow;
    ocol[ni] = o;
    bvn[ni] = (o < ODIM) ? bias[s * ODIM + o] : 0.f;
  }
  #pragma unroll
  for (int mi = 0; mi < 5; mi++){
    int rbase = wm + (mi << 4) + (fk << 2);
    #pragma unroll
    for (int jj = 0; jj < 4; jj++){
      int rr = rbase + jj;
      if (rr < cnt_loc){
        int orow = permL[rr];
        #pragma unroll
        for (int ni = 0; ni < 4; ni++){
          if (ocol[ni] < ODIM)
            out[(size_t)orow * ODIM + ocol[ni]] = acc[mi][ni][jj] + bvn[ni];
        }
      }
    }
  }
#undef STAGE
#undef TS
#undef TS0
#undef AOFF
#undef BOFF
#undef MF
#undef PHASE
#undef TILE
}

// ---------------- fallback: naive fp32 (only if ws too small) ----------------
__global__ __launch_bounds__(256) void naive_kernel(const float* __restrict__ x,
                                                    const int* __restrict__ sid,
                                                    const float* __restrict__ W,
                                                    const float* __restrict__ bias,
                                                    float* __restrict__ out){
  __shared__ float xr[KDIM];
  int row = blockIdx.x;
  int s = sid[row];
  for (int i = threadIdx.x; i < KDIM; i += 256) xr[i] = x[(size_t)row * KDIM + i];
  __syncthreads();
  int o = blockIdx.y * 256 + threadIdx.x;
  if (o >= ODIM) return;
  const float* w = W + (size_t)s * KDIM * ODIM + o;
  float acc = bias[s * ODIM + o];
  for (int k = 0; k < KDIM; k++) acc = fmaf(xr[k], w[(size_t)k * ODIM], acc);
  out[(size_t)row * ODIM + o] = acc;
}

extern "C" void kernel_launch(void* const* d_in, const int* in_sizes, int n_in,
                              void* d_out, int out_size, void* d_ws, size_t ws_size,
                              hipStream_t stream) {
  const float* x    = (const float*)d_in[0];
  const int*   sid  = (const int*)d_in[1];
  const float* W    = (const float*)d_in[2];
  const float* bias = (const float*)d_in[3];
  float* out = (float*)d_out;

  const size_t XS_BYTES = (size_t)NROWS * KDIM * 2;
  const size_t WT_BYTES = (size_t)NSUB * OPAD * KDIM * 2;
  const size_t need = 64 + (size_t)NROWS * 4 + XS_BYTES + WT_BYTES;

  if (ws_size < need){
    naive_kernel<<<dim3(NROWS, 4), 256, 0, stream>>>(x, sid, W, bias, out);
    return;
  }

  char* w = (char*)d_ws;
  int* counts  = (int*)w;                      // 8 ints
  int* offsets = counts + 8;                   // 8 ints
  int* perm    = (int*)(w + 64);               // 8192 ints
  unsigned short* xs = (unsigned short*)(w + 64 + (size_t)NROWS * 4);
  unsigned short* Wt = xs + (size_t)NROWS * KDIM;

  build_perm <<<NSUB, 256, 0, stream>>>(sid, counts, offsets, perm);
  prep_fused <<<NROWS + 4096, 256, 0, stream>>>(x, perm, xs, W, Wt);
  gemm_bf16  <<<NSUB * 4 * MT_MAX, 512, 0, stream>>>(xs, Wt, counts, offsets, perm, bias, out);
}

// Round 13
// 99.603 us; speedup vs baseline: 1.2525x; 1.1298x over previous
//
#include <hip/hip_runtime.h>
#include <hip/hip_bf16.h>
#include <cstdint>
#include <cstddef>

#define NROWS 8192
#define KDIM  2048
#define ODIM  1000
#define NSUB  8
#define OPAD  1024   // padded output dim for Wt

#define BM 160
#define BN 256
#define BK 64
#define MT_MAX 8                 // 8 x 160 = 1280 rows/subject covered
#define ASLOT (BM * BK)          // 10240 elems (20KB)
#define SLOT  ((BM + BN) * BK)   // 26624 elems (53248B)

typedef __attribute__((ext_vector_type(4))) float f32x4;
typedef __attribute__((ext_vector_type(8))) short short8v;
typedef __attribute__((ext_vector_type(4))) unsigned short u16x4;
typedef __attribute__((ext_vector_type(4))) int int4v;

__device__ __forceinline__ unsigned short f2bf(float f){
  unsigned u = __builtin_bit_cast(unsigned, f);
  unsigned r = (u + 0x7FFFu + ((u >> 16) & 1u)) >> 16;  // RNE
  return (unsigned short)r;
}

__device__ __forceinline__ void gload16(const void* g, void* l){
  __builtin_amdgcn_global_load_lds(
      (const __attribute__((address_space(1))) void*)g,
      (__attribute__((address_space(3))) void*)l, 16, 0, 0);
}

// ---------------- K1: build perm/counts/offsets in ONE kernel ----------------
__global__ __launch_bounds__(256) void build_perm(const int* __restrict__ sid,
                                                  int* __restrict__ counts,
                                                  int* __restrict__ offsets,
                                                  int* __restrict__ perm){
  int s = blockIdx.x;
  __shared__ int shs[NROWS];          // 32KB cached sid
  __shared__ int red_lt[4], red_eq[4], wsum[4];
  __shared__ int sh_base;

  int t = threadIdx.x, lane = t & 63, wv = t >> 6;

  int c_lt = 0, c_eq = 0;
  const int4v* sv = (const int4v*)sid;
  #pragma unroll
  for (int i = 0; i < NROWS / 4 / 256; i++){
    int idx = i * 256 + t;
    int4v v = sv[idx];
    *(int4v*)&shs[idx * 4] = v;
    #pragma unroll
    for (int e = 0; e < 4; e++){ c_lt += (v[e] < s); c_eq += (v[e] == s); }
  }
  #pragma unroll
  for (int d = 32; d >= 1; d >>= 1){
    c_lt += __shfl_xor(c_lt, d);
    c_eq += __shfl_xor(c_eq, d);
  }
  if (lane == 0){ red_lt[wv] = c_lt; red_eq[wv] = c_eq; }
  __syncthreads();
  if (t == 0){
    int lt = red_lt[0] + red_lt[1] + red_lt[2] + red_lt[3];
    int eq = red_eq[0] + red_eq[1] + red_eq[2] + red_eq[3];
    offsets[s] = lt;
    counts[s]  = eq;
    sh_base = lt;
  }
  __syncthreads();
  int base = sh_base;

  for (int c0 = 0; c0 < NROWS; c0 += 256){
    int v = shs[c0 + t];
    bool eq = (v == s);
    unsigned long long m = __ballot(eq);
    int rk = __popcll(m & ((1ull << lane) - 1ull));
    int wc = __popcll(m);
    if (lane == 0) wsum[wv] = wc;
    __syncthreads();
    int woff = 0;
    #pragma unroll
    for (int w = 0; w < 4; w++) if (w < wv) woff += wsum[w];
    int tot = wsum[0] + wsum[1] + wsum[2] + wsum[3];
    if (eq) perm[base + woff + rk] = c0 + t;
    base += tot;
    __syncthreads();
  }
}

// ---------------- K2: fused gather(x->xs bf16 sorted) + transpose(W->Wt bf16) ----------------
__global__ __launch_bounds__(256) void prep_fused(const float* __restrict__ x,
                                                  const int* __restrict__ perm,
                                                  unsigned short* __restrict__ xs,
                                                  const float* __restrict__ W,
                                                  unsigned short* __restrict__ Wt){
  __shared__ float tile[64][65];
  int b = blockIdx.x;
  int t = threadIdx.x;
  if (b < NROWS){
    int orow = perm[b];
    const f32x4* src = (const f32x4*)(x + (size_t)orow * KDIM);
    u16x4* dst = (u16x4*)(xs + (size_t)b * KDIM);
    #pragma unroll
    for (int c = 0; c < 2; c++){
      f32x4 v = src[c * 256 + t];
      u16x4 o;
      o[0] = f2bf(v[0]); o[1] = f2bf(v[1]); o[2] = f2bf(v[2]); o[3] = f2bf(v[3]);
      dst[c * 256 + t] = o;
    }
    return;
  }
  int b2 = b - NROWS;
  int s  = b2 >> 9;
  int kt = (b2 >> 4) & 31;
  int ot = b2 & 15;
  int k0 = kt * 64, o0 = ot * 64;
  int ol = t & 63, kr = t >> 6;
  const float* src = W + ((size_t)s * KDIM + k0) * ODIM + o0;
  bool oval = (o0 + ol) < ODIM;
  #pragma unroll
  for (int it = 0; it < 16; it++){
    int k = kr * 16 + it;
    tile[k][ol] = oval ? src[(size_t)k * ODIM + ol] : 0.f;
  }
  __syncthreads();
  int kp = t & 31, orow = t >> 5;
  unsigned short* dst = Wt + ((size_t)(s * OPAD + o0)) * KDIM + k0;
  #pragma unroll
  for (int it = 0; it < 8; it++){
    int o = orow + it * 8;
    bool valid = (o0 + o) < ODIM;        // pad rows -> zeros
    unsigned lo = valid ? (unsigned)f2bf(tile[kp * 2][o])     : 0u;
    unsigned hi = valid ? (unsigned)f2bf(tile[kp * 2 + 1][o]) : 0u;
    *(unsigned*)(dst + (size_t)o * KDIM + kp * 2) = lo | (hi << 16);
  }
}

// ---------------- K3: grouped bf16 MFMA GEMM, 160x256, 8 waves, 3-slot ring ----------------
// R12 geometry + m201 8-phase discipline: per K-tile TWO phases, each
// {9 ds_read + stage-part -> barrier -> lgkmcnt(0) -> setprio 20 MFMA ->
//  (counted vmcnt at tile end) -> barrier}. vmcnt(7/6) never drains in loop.
__global__ __launch_bounds__(512, 1) void gemm_bf16(
    const unsigned short* __restrict__ xs,   // [8192][2048] bf16 (sorted)
    const unsigned short* __restrict__ Wt,   // [8][1024][2048] bf16
    const int* __restrict__ counts,
    const int* __restrict__ offsets,
    const int* __restrict__ perm,
    const float* __restrict__ bias,          // [8][1000]
    float* __restrict__ out)                 // [8192][1000]
{
  int b  = blockIdx.x;
  int s  = b & 7;                 // subject == XCD (hw round-robins bid%8)
  int r  = b >> 3;
  int nt = r & 3;                 // 0..3 (256-col tiles over OPAD)
  int mt = r >> 2;                // 0..7
  int cnt = counts[s];
  int loc0 = mt * BM;
  if (loc0 >= cnt) return;
  int row0 = offsets[s] + loc0;
  int cnt_loc = cnt - loc0;

  __shared__ unsigned short L[3 * SLOT];     // 3 x 53248B ring (159744B)
  __shared__ int permL[BM];                  // +640B => 160384 <= 163840

  int t = threadIdx.x;
  int lane = t & 63;
  int wave = t >> 6;              // 0..7

  int wm = (wave >> 2) * 80;      // 2M x 4N waves; wave-tile 80x64
  int wn = (wave & 3) << 6;
  int frow = lane & 15, fk = lane >> 4;
  int axor = frow & 7;

  // staging geometry (R4-verified, 0 bank conflicts): 1KB chunk = 8 rows x
  // 128B; phys 16B-slot (lane&7) holds logical (lane&7)^(row&7).
  int srck = (((lane & 7) ^ ((lane >> 3) & 7)) << 3);
  size_t gA[5]; unsigned loA[5];
  size_t gB[6]; unsigned loB[6];
  if (wave < 4){
    #pragma unroll
    for (int i = 0; i < 5; i++){
      int ca  = wave * 5 + i;                // 0..19
      int row = (ca << 3) + (lane >> 3);     // 0..159
      int ra  = row0 + row; if (ra > NROWS - 1) ra = NROWS - 1;
      gA[i]  = (size_t)ra * KDIM + srck;
      loA[i] = (unsigned)((ca << 9) + (lane << 3));
    }
    #pragma unroll
    for (int j = 0; j < 2; j++){
      int cb  = wave * 2 + j;                // 0..7
      int row = (cb << 3) + (lane >> 3);     // 0..63
      gB[j]  = ((size_t)(s * OPAD + nt * BN + row)) * KDIM + srck;
      loB[j] = (unsigned)(ASLOT + (cb << 9) + (lane << 3));
    }
  } else {
    #pragma unroll
    for (int j = 0; j < 6; j++){
      int cb  = 8 + (wave - 4) * 6 + j;      // 8..31
      int row = (cb << 3) + (lane >> 3);     // 64..255
      gB[j]  = ((size_t)(s * OPAD + nt * BN + row)) * KDIM + srck;
      loB[j] = (unsigned)(ASLOT + (cb << 9) + (lane << 3));
    }
  }

  f32x4 acc[5][4];
  #pragma unroll
  for (int i = 0; i < 5; i++)
    #pragma unroll
    for (int j = 0; j < 4; j++)
      #pragma unroll
      for (int e = 0; e < 4; e++) acc[i][j][e] = 0.f;

// full stage (prologue only): 7 loads (waves 0-3) / 6 loads (waves 4-7)
#define STAGE_FULL(sl, koff) do { \
    unsigned short* Ls = &L[(sl) * SLOT]; \
    if (wave < 4){ \
      gload16(xs + gA[0] + (koff), (void*)(Ls + loA[0])); \
      gload16(xs + gA[1] + (koff), (void*)(Ls + loA[1])); \
      gload16(xs + gA[2] + (koff), (void*)(Ls + loA[2])); \
      gload16(xs + gA[3] + (koff), (void*)(Ls + loA[3])); \
      gload16(xs + gA[4] + (koff), (void*)(Ls + loA[4])); \
      gload16(Wt + gB[0] + (koff), (void*)(Ls + loB[0])); \
      gload16(Wt + gB[1] + (koff), (void*)(Ls + loB[1])); \
    } else { \
      gload16(Wt + gB[0] + (koff), (void*)(Ls + loB[0])); \
      gload16(Wt + gB[1] + (koff), (void*)(Ls + loB[1])); \
      gload16(Wt + gB[2] + (koff), (void*)(Ls + loB[2])); \
      gload16(Wt + gB[3] + (koff), (void*)(Ls + loB[3])); \
      gload16(Wt + gB[4] + (koff), (void*)(Ls + loB[4])); \
      gload16(Wt + gB[5] + (koff), (void*)(Ls + loB[5])); \
    } \
  } while (0)

// stage split across the tile's two phases: P0 = 5 (3) loads, P1 = 2 (3)
#define STAGE_P0(sl, koff) do { \
    unsigned short* Ls = &L[(sl) * SLOT]; \
    if (wave < 4){ \
      gload16(xs + gA[0] + (koff), (void*)(Ls + loA[0])); \
      gload16(xs + gA[1] + (koff), (void*)(Ls + loA[1])); \
      gload16(xs + gA[2] + (koff), (void*)(Ls + loA[2])); \
      gload16(xs + gA[3] + (koff), (void*)(Ls + loA[3])); \
      gload16(xs + gA[4] + (koff), (void*)(Ls + loA[4])); \
    } else { \
      gload16(Wt + gB[0] + (koff), (void*)(Ls + loB[0])); \
      gload16(Wt + gB[1] + (koff), (void*)(Ls + loB[1])); \
      gload16(Wt + gB[2] + (koff), (void*)(Ls + loB[2])); \
    } \
  } while (0)
#define STAGE_P1(sl, koff) do { \
    unsigned short* Ls = &L[(sl) * SLOT]; \
    if (wave < 4){ \
      gload16(Wt + gB[0] + (koff), (void*)(Ls + loB[0])); \
      gload16(Wt + gB[1] + (koff), (void*)(Ls + loB[1])); \
    } else { \
      gload16(Wt + gB[3] + (koff), (void*)(Ls + loB[3])); \
      gload16(Wt + gB[4] + (koff), (void*)(Ls + loB[4])); \
      gload16(Wt + gB[5] + (koff), (void*)(Ls + loB[5])); \
    } \
  } while (0)

// counted end-of-tile wait: drain NEXT tile's stage, leave t+2's in flight
#define VMN() do { \
    if (wave < 4) asm volatile("s_waitcnt vmcnt(7)" ::: "memory"); \
    else          asm volatile("s_waitcnt vmcnt(6)" ::: "memory"); \
    __builtin_amdgcn_sched_barrier(0); \
  } while (0)
#define VM0() do { \
    asm volatile("s_waitcnt vmcnt(0)" ::: "memory"); \
    __builtin_amdgcn_sched_barrier(0); \
  } while (0)

#define AOFF(mi, ks) (((wm + ((mi) << 4) + frow) << 6) + ((((ks) * 4 + fk) ^ axor) << 3))
#define BOFF(ni, ks) (ASLOT + ((wn + ((ni) << 4) + frow) << 6) + ((((ks) * 4 + fk) ^ axor) << 3))
#define MF(mi, ni, av, bv) acc[mi][ni] = __builtin_amdgcn_mfma_f32_16x16x32_bf16(av, bv, acc[mi][ni], 0, 0, 0)

// one phase (m201 discipline): 9 ds_read + stage-part -> barrier ->
// lgkm(0) -> setprio MFMA cluster -> (end wait) -> barrier
#define PH(sl, ks, STG, ENDW) do { \
    const unsigned short* Lb = &L[(sl) * SLOT]; \
    short8v a0 = *(const short8v*)&Lb[AOFF(0, ks)]; \
    short8v a1 = *(const short8v*)&Lb[AOFF(1, ks)]; \
    short8v a2 = *(const short8v*)&Lb[AOFF(2, ks)]; \
    short8v a3 = *(const short8v*)&Lb[AOFF(3, ks)]; \
    short8v a4 = *(const short8v*)&Lb[AOFF(4, ks)]; \
    short8v b0 = *(const short8v*)&Lb[BOFF(0, ks)]; \
    short8v b1 = *(const short8v*)&Lb[BOFF(1, ks)]; \
    short8v b2 = *(const short8v*)&Lb[BOFF(2, ks)]; \
    short8v b3 = *(const short8v*)&Lb[BOFF(3, ks)]; \
    STG; \
    __builtin_amdgcn_s_barrier(); \
    asm volatile("s_waitcnt lgkmcnt(0)" ::: "memory"); \
    __builtin_amdgcn_sched_barrier(0); \
    __builtin_amdgcn_s_setprio(1); \
    MF(0, 0, a0, b0); MF(1, 0, a1, b0); MF(2, 0, a2, b0); MF(3, 0, a3, b0); MF(4, 0, a4, b0); \
    MF(0, 1, a0, b1); MF(1, 1, a1, b1); MF(2, 1, a2, b1); MF(3, 1, a3, b1); MF(4, 1, a4, b1); \
    MF(0, 2, a0, b2); MF(1, 2, a1, b2); MF(2, 2, a2, b2); MF(3, 2, a3, b2); MF(4, 2, a4, b2); \
    MF(0, 3, a0, b3); MF(1, 3, a1, b3); MF(2, 3, a2, b3); MF(3, 3, a3, b3); MF(4, 3, a4, b3); \
    __builtin_amdgcn_s_setprio(0); \
    ENDW; \
    __builtin_amdgcn_s_barrier(); \
  } while (0)

  // prologue: perm -> permL (drained BEFORE staging so vmcnt counts stay exact)
  {
    int pr = t;
    if (pr >= 320) pr -= 320;
    if (pr >= 160) pr -= 160;               // pr in [0,160), duplicates benign
    int pidx = row0 + pr; if (pidx > NROWS - 1) pidx = NROWS - 1;
    int pl = perm[pidx];
    asm volatile("s_waitcnt vmcnt(0)" ::: "memory");
    __builtin_amdgcn_sched_barrier(0);
    permL[pr] = pl;
  }
  STAGE_FULL(0, 0);
  STAGE_FULL(1, BK);
  VMN();                                     // drain stage 0, leave stage 1
  __builtin_amdgcn_s_barrier();

  // main loop: tiles 0..29 (10 iters x 3 slots); stage t+2 split across phases
  for (int i = 0; i < 10; ++i){
    int kb = i * 3 * BK;
    PH(0, 0, STAGE_P0(2, kb + 2 * BK), );
    PH(0, 1, STAGE_P1(2, kb + 2 * BK), VMN());
    PH(1, 0, STAGE_P0(0, kb + 3 * BK), );
    PH(1, 1, STAGE_P1(0, kb + 3 * BK), VMN());
    PH(2, 0, STAGE_P0(1, kb + 4 * BK), );
    PH(2, 1, STAGE_P1(1, kb + 4 * BK), VMN());
  }
  // tail: tile 30 (slot 0) -> drain all for tile 31; tile 31 (slot 1)
  PH(0, 0, , );
  PH(0, 1, , VM0());
  PH(1, 0, , );
  PH(1, 1, , );

  // epilogue: C/D layout col=lane&15, row=(lane>>4)*4+reg
  float bvn[4]; int ocol[4];
  #pragma unroll
  for (int ni = 0; ni < 4; ni++){
    int o = nt * BN + wn + (ni << 4) + frow;
    ocol[ni] = o;
    bvn[ni] = (o < ODIM) ? bias[s * ODIM + o] : 0.f;
  }
  #pragma unroll
  for (int mi = 0; mi < 5; mi++){
    int rbase = wm + (mi << 4) + (fk << 2);
    #pragma unroll
    for (int jj = 0; jj < 4; jj++){
      int rr = rbase + jj;
      if (rr < cnt_loc){
        int orow = permL[rr];
        #pragma unroll
        for (int ni = 0; ni < 4; ni++){
          if (ocol[ni] < ODIM)
            out[(size_t)orow * ODIM + ocol[ni]] = acc[mi][ni][jj] + bvn[ni];
        }
      }
    }
  }
#undef STAGE_FULL
#undef STAGE_P0
#undef STAGE_P1
#undef VMN
#undef VM0
#undef AOFF
#undef BOFF
#undef MF
#undef PH
}

// ---------------- fallback: naive fp32 (only if ws too small) ----------------
__global__ __launch_bounds__(256) void naive_kernel(const float* __restrict__ x,
                                                    const int* __restrict__ sid,
                                                    const float* __restrict__ W,
                                                    const float* __restrict__ bias,
                                                    float* __restrict__ out){
  __shared__ float xr[KDIM];
  int row = blockIdx.x;
  int s = sid[row];
  for (int i = threadIdx.x; i < KDIM; i += 256) xr[i] = x[(size_t)row * KDIM + i];
  __syncthreads();
  int o = blockIdx.y * 256 + threadIdx.x;
  if (o >= ODIM) return;
  const float* w = W + (size_t)s * KDIM * ODIM + o;
  float acc = bias[s * ODIM + o];
  for (int k = 0; k < KDIM; k++) acc = fmaf(xr[k], w[(size_t)k * ODIM], acc);
  out[(size_t)row * ODIM + o] = acc;
}

extern "C" void kernel_launch(void* const* d_in, const int* in_sizes, int n_in,
                              void* d_out, int out_size, void* d_ws, size_t ws_size,
                              hipStream_t stream) {
  const float* x    = (const float*)d_in[0];
  const int*   sid  = (const int*)d_in[1];
  const float* W    = (const float*)d_in[2];
  const float* bias = (const float*)d_in[3];
  float* out = (float*)d_out;

  const size_t XS_BYTES = (size_t)NROWS * KDIM * 2;
  const size_t WT_BYTES = (size_t)NSUB * OPAD * KDIM * 2;
  const size_t need = 64 + (size_t)NROWS * 4 + XS_BYTES + WT_BYTES;

  if (ws_size < need){
    naive_kernel<<<dim3(NROWS, 4), 256, 0, stream>>>(x, sid, W, bias, out);
    return;
  }

  char* w = (char*)d_ws;
  int* counts  = (int*)w;                      // 8 ints
  int* offsets = counts + 8;                   // 8 ints
  int* perm    = (int*)(w + 64);               // 8192 ints
  unsigned short* xs = (unsigned short*)(w + 64 + (size_t)NROWS * 4);
  unsigned short* Wt = xs + (size_t)NROWS * KDIM;

  build_perm <<<NSUB, 256, 0, stream>>>(sid, counts, offsets, perm);
  prep_fused <<<NROWS + 4096, 256, 0, stream>>>(x, perm, xs, W, Wt);
  gemm_bf16  <<<NSUB * 4 * MT_MAX, 512, 0, stream>>>(xs, Wt, counts, offsets, perm, bias, out);
}